// Round 7
// baseline (209.170 us; speedup 1.0000x reference)
//
#include <hip/hip_runtime.h>
#include <hip/hip_bf16.h>
#include <hip/hip_cooperative_groups.h>
#include <math.h>

namespace cg = cooperative_groups;

// Problem constants: R,C,D,ORDER = 2048,2048,64,3; O=4
#define R_DIM 2048
#define C_DIM 2048
#define D_DIM 64
// Factorization: dist^2[r,c] = sum_k A[r,k]*B[c,k] + ||zc||^2 with
//   k in [0,256): A = z_rows[o][r][d], B = -2*coef_o(t_c)*z_cols[c][d]
//   k in [256,272): A = Gram[r] (4x4 row-major), B = coef_o*coef_o' products
//   k in [272,288): zero pad
#define K_TOT 288

typedef __attribute__((ext_vector_type(8))) short short8;   // bf16x8 MFMA frag
typedef __attribute__((ext_vector_type(4))) float floatx4;  // fp32x4 acc

__device__ __forceinline__ ushort f2bf(float f) {  // RNE float->bf16
  unsigned u = __float_as_uint(f);
  return (ushort)((u + 0x7FFFu + ((u >> 16) & 1u)) >> 16);
}

// Single cooperative kernel: prep phase -> grid sync -> GEMM+epilogue phase.
// Grid 512 x 256 thr, __launch_bounds__(256,2) => <=256 VGPR, 2 blocks/CU
// guaranteed co-resident (512 <= 256*2) so cooperative launch validates.
__launch_bounds__(256, 2)
__global__ void fused_kernel(const int* __restrict__ events,
                             const float* __restrict__ col_times,
                             const float* __restrict__ z_rows,
                             const float* __restrict__ z_cols,
                             const float* __restrict__ gamma_rows,
                             const float* __restrict__ gamma_cols,
                             ushort* __restrict__ Ab,
                             ushort* __restrict__ Bb,
                             float* __restrict__ nzc,
                             unsigned* __restrict__ Wb,
                             float* __restrict__ out) {
  __shared__ float red[4];
  const int bid = blockIdx.x;
  const int t = threadIdx.x;
  const int widx = t >> 6, lane = t & 63;

  if (bid == 0 && t == 0) out[0] = 0.0f;  // visible after fence+grid sync

  // ================= phase 1: prep (4 rows/cols per block) =================
  const int r0 = bid * 4;

  // ---- events bit-pack: 4 rows x 8KB, coalesced int4, shuffle-OR -> u32 ----
#pragma unroll
  for (int rr = 0; rr < 4; ++rr) {
    const int r = r0 + rr;
    const int4 e0 = *(const int4*)&events[(size_t)r * C_DIM + t * 4];
    const int4 e1 = *(const int4*)&events[(size_t)r * C_DIM + 1024 + t * 4];
    unsigned w0 = ((unsigned)(e0.x & 1) | ((unsigned)(e0.y & 1) << 1) |
                   ((unsigned)(e0.z & 1) << 2) | ((unsigned)(e0.w & 1) << 3))
                  << ((t & 7) * 4);
    w0 |= __shfl_xor((int)w0, 1); w0 |= __shfl_xor((int)w0, 2);
    w0 |= __shfl_xor((int)w0, 4);
    if ((t & 7) == 0) Wb[r * 64 + (t >> 3)] = w0;
    unsigned w1 = ((unsigned)(e1.x & 1) | ((unsigned)(e1.y & 1) << 1) |
                   ((unsigned)(e1.z & 1) << 2) | ((unsigned)(e1.w & 1) << 3))
                  << ((t & 7) * 4);
    w1 |= __shfl_xor((int)w1, 1); w1 |= __shfl_xor((int)w1, 2);
    w1 |= __shfl_xor((int)w1, 4);
    if ((t & 7) == 0) Wb[r * 64 + 32 + (t >> 3)] = w1;
  }

  // ---- wave widx handles Ab row (r0+widx) then Bb row (r0+widx) ----
  {
    const int r = r0 + widx;
    float zv[4];
#pragma unroll
    for (int o = 0; o < 4; ++o) {
      zv[o] = z_rows[(size_t)(o * R_DIM + r) * D_DIM + lane];
      Ab[(size_t)r * K_TOT + o * 64 + lane] = f2bf(zv[o]);
    }
    float g00 = zv[0] * zv[0], g01 = zv[0] * zv[1], g02 = zv[0] * zv[2],
          g03 = zv[0] * zv[3], g11 = zv[1] * zv[1], g12 = zv[1] * zv[2],
          g13 = zv[1] * zv[3], g22 = zv[2] * zv[2], g23 = zv[2] * zv[3],
          g33 = zv[3] * zv[3];
#pragma unroll
    for (int off = 32; off > 0; off >>= 1) {
      g00 += __shfl_xor(g00, off); g01 += __shfl_xor(g01, off);
      g02 += __shfl_xor(g02, off); g03 += __shfl_xor(g03, off);
      g11 += __shfl_xor(g11, off); g12 += __shfl_xor(g12, off);
      g13 += __shfl_xor(g13, off); g22 += __shfl_xor(g22, off);
      g23 += __shfl_xor(g23, off); g33 += __shfl_xor(g33, off);
    }
    if (lane == 0) {
      ushort* e = Ab + (size_t)r * K_TOT + 256;  // symmetric 4x4 Gram
      e[0] = f2bf(g00);  e[1] = f2bf(g01);  e[2] = f2bf(g02);  e[3] = f2bf(g03);
      e[4] = f2bf(g01);  e[5] = f2bf(g11);  e[6] = f2bf(g12);  e[7] = f2bf(g13);
      e[8] = f2bf(g02);  e[9] = f2bf(g12);  e[10] = f2bf(g22); e[11] = f2bf(g23);
      e[12] = f2bf(g03); e[13] = f2bf(g13); e[14] = f2bf(g23); e[15] = f2bf(g33);
    }
    if (lane < 16) Ab[(size_t)r * K_TOT + 272 + lane] = 0;  // pad

    const float tt = col_times[r];
    float cf[4];
    cf[0] = 1.0f; cf[1] = tt; cf[2] = tt * tt * 0.5f;
    cf[3] = cf[2] * tt * (1.0f / 3.0f);
    const float zc = z_cols[(size_t)r * D_DIM + lane];
#pragma unroll
    for (int o = 0; o < 4; ++o)
      Bb[(size_t)r * K_TOT + o * 64 + lane] = f2bf(-2.0f * cf[o] * zc);
    float q = zc * zc;
#pragma unroll
    for (int off = 32; off > 0; off >>= 1) q += __shfl_xor(q, off);
    if (lane == 0) {
      nzc[r] = q;
      ushort* e = Bb + (size_t)r * K_TOT + 256;
#pragma unroll
      for (int i = 0; i < 16; ++i) e[i] = f2bf(cf[i >> 2] * cf[i & 3]);
    }
    if (lane < 16) Bb[(size_t)r * K_TOT + 272 + lane] = 0;  // pad
  }

  // ============ grid-wide sync with cross-XCD visibility ============
  __threadfence();           // agent-scope release: writeback dirty L2
  cg::this_grid().sync();
  __threadfence();           // agent-scope acquire: invalidate stale lines

  // ================= phase 2: two 64x64 GEMM tiles per block ===============
  const int wm = widx & 1, wn = widx >> 1;  // wave pos in 2x2
  const int lm = lane & 15, kg = lane >> 4;
  float lsum = 0.0f;

#pragma unroll
  for (int ti = 0; ti < 2; ++ti) {
    const int tile = bid + ti * 512;
    const int m0 = (tile >> 5) * 64, c0 = (tile & 31) * 64;

    // lane base pointers; A-operand layout: lane holds A[m=lane&15][k=kg*8+j]
    const ushort* a0p = Ab + (size_t)(m0 + wm * 32 + lm) * K_TOT + kg * 8;
    const ushort* a1p = a0p + 16 * K_TOT;
    const ushort* b0p = Bb + (size_t)(c0 + wn * 32 + lm) * K_TOT + kg * 8;
    const ushort* b1p = b0p + 16 * K_TOT;

    floatx4 acc[2][2];
#pragma unroll
    for (int i = 0; i < 2; ++i)
#pragma unroll
      for (int j = 0; j < 2; ++j) acc[i][j] = (floatx4){0.f, 0.f, 0.f, 0.f};

#pragma unroll
    for (int kt = 0; kt < 9; ++kt) {
      const short8 a0 = *(const short8*)(a0p + kt * 32);
      const short8 a1 = *(const short8*)(a1p + kt * 32);
      const short8 b0 = *(const short8*)(b0p + kt * 32);
      const short8 b1 = *(const short8*)(b1p + kt * 32);
      acc[0][0] = __builtin_amdgcn_mfma_f32_16x16x32_bf16(a0, b0, acc[0][0], 0, 0, 0);
      acc[0][1] = __builtin_amdgcn_mfma_f32_16x16x32_bf16(a0, b1, acc[0][1], 0, 0, 0);
      acc[1][0] = __builtin_amdgcn_mfma_f32_16x16x32_bf16(a1, b0, acc[1][0], 0, 0, 0);
      acc[1][1] = __builtin_amdgcn_mfma_f32_16x16x32_bf16(a1, b1, acc[1][1], 0, 0, 0);
    }

    // Epilogue. C/D layout (m89): col = lane&15, row = (lane>>4)*4 + reg.
    // loss = softplus(logit) - ev*logit (branchless; ev from bit-pack)
#pragma unroll
    for (int nt = 0; nt < 2; ++nt) {
      const int c = c0 + wn * 32 + nt * 16 + lm;
      const float gc = gamma_cols[c];
      const float nz = nzc[c];
      const int cword = c >> 5, cbit = c & 31;
#pragma unroll
      for (int mt = 0; mt < 2; ++mt) {
        const int rbase = m0 + wm * 32 + mt * 16 + kg * 4;
#pragma unroll
        for (int j = 0; j < 4; ++j) {
          const int r = rbase + j;
          const float evf = (float)((Wb[r * 64 + cword] >> cbit) & 1u);
          const float d2 = acc[mt][nt][j] + nz;
          const float dist = sqrtf(fmaxf(d2, 0.0f));
          const float logit = gamma_rows[r] + gc - dist;
          lsum += fmaxf(logit, 0.0f) + __logf(1.0f + __expf(-fabsf(logit))) -
                  evf * logit;
        }
      }
    }
  }

#pragma unroll
  for (int off = 32; off > 0; off >>= 1) lsum += __shfl_down(lsum, off);
  if (lane == 0) red[widx] = lsum;
  __syncthreads();
  if (t == 0) atomicAdd(out, red[0] + red[1] + red[2] + red[3]);
}

extern "C" void kernel_launch(void* const* d_in, const int* in_sizes, int n_in,
                              void* d_out, int out_size, void* d_ws, size_t ws_size,
                              hipStream_t stream) {
  const int* events = (const int*)d_in[0];
  const float* col_times = (const float*)d_in[1];
  const float* z_rows = (const float*)d_in[2];
  const float* z_cols = (const float*)d_in[3];
  const float* gamma_rows = (const float*)d_in[4];
  const float* gamma_cols = (const float*)d_in[5];
  float* out = (float*)d_out;

  ushort* Ab = (ushort*)d_ws;                         // 2048*288 bf16
  ushort* Bb = Ab + (size_t)R_DIM * K_TOT;            // 2048*288 bf16
  float* nzc = (float*)(Bb + (size_t)C_DIM * K_TOT);  // 2048 f32
  unsigned* Wb = (unsigned*)(nzc + C_DIM);            // 2048*64 u32 bit-pack

  void* args[] = {(void*)&events, (void*)&col_times, (void*)&z_rows,
                  (void*)&z_cols, (void*)&gamma_rows, (void*)&gamma_cols,
                  (void*)&Ab,     (void*)&Bb,         (void*)&nzc,
                  (void*)&Wb,     (void*)&out};
  hipLaunchCooperativeKernel((void*)fused_kernel, dim3(512), dim3(256), args, 0,
                             stream);
}

// Round 8
// 95.408 us; speedup vs baseline: 2.1924x; 2.1924x over previous
//
#include <hip/hip_runtime.h>
#include <hip/hip_bf16.h>
#include <math.h>

// Problem constants: R,C,D,ORDER = 2048,2048,64,3; O=4
#define R_DIM 2048
#define C_DIM 2048
#define D_DIM 64
// Factorization: dist^2[r,c] = sum_k A[r,k]*B[c,k] + ||zc||^2 with
//   k in [0,256): A = z_rows[o][r][d], B = -2*coef_o(t_c)*z_cols[c][d]
//   k in [256,272): A = Gram[r] (4x4 row-major), B = coef_o*coef_o' products
//   k in [272,288): zero pad
#define K_TOT 288

typedef __attribute__((ext_vector_type(8))) short short8;   // bf16x8 MFMA frag
typedef __attribute__((ext_vector_type(4))) float floatx4;  // fp32x4 acc

__device__ __forceinline__ ushort f2bf(float f) {  // RNE float->bf16
  unsigned u = __float_as_uint(f);
  return (ushort)((u + 0x7FFFu + ((u >> 16) & 1u)) >> 16);
}

// ---------------- prep: Ab/Bb bf16 matrices, nzc, event bit-pack, out=0 ------
// (unchanged from round 6 — passed, streaming-bound, ~4 us)
__global__ void prep_kernel(const int* __restrict__ events,
                            const float* __restrict__ col_times,
                            const float* __restrict__ z_rows,
                            const float* __restrict__ z_cols,
                            ushort* __restrict__ Ab,
                            ushort* __restrict__ Bb,
                            float* __restrict__ nzc,
                            unsigned* __restrict__ Wb,
                            float* __restrict__ out) {
  const int b = blockIdx.x;
  const int t = threadIdx.x;
  const int lane = t & 63;

  if (b == 0 && t == 0) out[0] = 0.0f;  // stream order: before pair_kernel

  // ---- events bit-pack: row b = 8KB contiguous, 2 coalesced int4 rounds ----
  const int4 e0 = *(const int4*)&events[(size_t)b * C_DIM + t * 4];
  const int4 e1 = *(const int4*)&events[(size_t)b * C_DIM + 1024 + t * 4];
  {
    unsigned w0 = ((unsigned)(e0.x & 1) | ((unsigned)(e0.y & 1) << 1) |
                   ((unsigned)(e0.z & 1) << 2) | ((unsigned)(e0.w & 1) << 3))
                  << ((t & 7) * 4);
    w0 |= __shfl_xor((int)w0, 1); w0 |= __shfl_xor((int)w0, 2);
    w0 |= __shfl_xor((int)w0, 4);
    if ((t & 7) == 0) Wb[b * 64 + (t >> 3)] = w0;
    unsigned w1 = ((unsigned)(e1.x & 1) | ((unsigned)(e1.y & 1) << 1) |
                   ((unsigned)(e1.z & 1) << 2) | ((unsigned)(e1.w & 1) << 3))
                  << ((t & 7) * 4);
    w1 |= __shfl_xor((int)w1, 1); w1 |= __shfl_xor((int)w1, 2);
    w1 |= __shfl_xor((int)w1, 4);
    if ((t & 7) == 0) Wb[b * 64 + 32 + (t >> 3)] = w1;
  }

  if (t < 64) {
    // ---- Ab row b ----
    float zv[4];
#pragma unroll
    for (int o = 0; o < 4; ++o) {
      zv[o] = z_rows[(size_t)(o * R_DIM + b) * D_DIM + lane];
      Ab[(size_t)b * K_TOT + o * 64 + lane] = f2bf(zv[o]);
    }
    float g00 = zv[0] * zv[0], g01 = zv[0] * zv[1], g02 = zv[0] * zv[2],
          g03 = zv[0] * zv[3], g11 = zv[1] * zv[1], g12 = zv[1] * zv[2],
          g13 = zv[1] * zv[3], g22 = zv[2] * zv[2], g23 = zv[2] * zv[3],
          g33 = zv[3] * zv[3];
#pragma unroll
    for (int off = 32; off > 0; off >>= 1) {
      g00 += __shfl_xor(g00, off); g01 += __shfl_xor(g01, off);
      g02 += __shfl_xor(g02, off); g03 += __shfl_xor(g03, off);
      g11 += __shfl_xor(g11, off); g12 += __shfl_xor(g12, off);
      g13 += __shfl_xor(g13, off); g22 += __shfl_xor(g22, off);
      g23 += __shfl_xor(g23, off); g33 += __shfl_xor(g33, off);
    }
    if (lane == 0) {
      ushort* e = Ab + (size_t)b * K_TOT + 256;  // symmetric 4x4
      e[0] = f2bf(g00);  e[1] = f2bf(g01);  e[2] = f2bf(g02);  e[3] = f2bf(g03);
      e[4] = f2bf(g01);  e[5] = f2bf(g11);  e[6] = f2bf(g12);  e[7] = f2bf(g13);
      e[8] = f2bf(g02);  e[9] = f2bf(g12);  e[10] = f2bf(g22); e[11] = f2bf(g23);
      e[12] = f2bf(g03); e[13] = f2bf(g13); e[14] = f2bf(g23); e[15] = f2bf(g33);
    }
    if (lane < 16) Ab[(size_t)b * K_TOT + 272 + lane] = 0;  // pad
  } else if (t < 128) {
    // ---- Bb row b + nzc ----
    const float tt = col_times[b];
    float cf[4];
    cf[0] = 1.0f; cf[1] = tt; cf[2] = tt * tt * 0.5f;
    cf[3] = cf[2] * tt * (1.0f / 3.0f);
    const float zc = z_cols[(size_t)b * D_DIM + lane];
#pragma unroll
    for (int o = 0; o < 4; ++o)
      Bb[(size_t)b * K_TOT + o * 64 + lane] = f2bf(-2.0f * cf[o] * zc);
    float q = zc * zc;
#pragma unroll
    for (int off = 32; off > 0; off >>= 1) q += __shfl_xor(q, off);
    if (lane == 0) {
      nzc[b] = q;
      ushort* e = Bb + (size_t)b * K_TOT + 256;
#pragma unroll
      for (int i = 0; i < 16; ++i) e[i] = f2bf(cf[i >> 2] * cf[i & 3]);
    }
    if (lane < 16) Bb[(size_t)b * K_TOT + 272 + lane] = 0;  // pad
  }
}

// ---------------- pair: register-direct MFMA GEMM, latency-optimized --------
// 64x64 block tile, 4 waves in 2x2 (32x32/wave), grid 32x32 = 1024 blocks,
// 16 waves/CU. Epilogue inputs (Wb bits, gammas, nzc) issued at kernel START
// and pinned with an asm use-barrier mid-K-loop so the compiler cannot sink
// them into the epilogue (the r4/r5 latency bug). K-loop software-pipelined
// with explicit next-fragment registers.
__launch_bounds__(256, 4)
__global__ void pair_kernel(const float* __restrict__ gamma_rows,
                            const float* __restrict__ gamma_cols,
                            const ushort* __restrict__ Ab,
                            const ushort* __restrict__ Bb,
                            const float* __restrict__ nzc,
                            const unsigned* __restrict__ Wb,
                            float* __restrict__ out) {
  __shared__ float red[4];
  const int t = threadIdx.x;
  const int widx = t >> 6, lane = t & 63;
  const int m0 = blockIdx.y * 64, c0 = blockIdx.x * 64;
  const int wm = widx & 1, wn = widx >> 1;  // wave pos in 2x2
  const int lm = lane & 15, kg = lane >> 4;

  // ---- epilogue inputs: issue FIRST, consume at the very end ----
  // cword = c>>5 is the same for nt=0,1 (c0 64-aligned, nt*16+lm < 32)
  const int cw = (c0 >> 5) + wn;
  unsigned wbits[8];
  float grv[8];
#pragma unroll
  for (int mt = 0; mt < 2; ++mt)
#pragma unroll
    for (int j = 0; j < 4; ++j) {
      const int r = m0 + wm * 32 + mt * 16 + kg * 4 + j;
      wbits[mt * 4 + j] = Wb[r * 64 + cw];
      grv[mt * 4 + j] = gamma_rows[r];
    }
  float gcv[2], nzv[2];
#pragma unroll
  for (int nt = 0; nt < 2; ++nt) {
    const int c = c0 + wn * 32 + nt * 16 + lm;
    gcv[nt] = gamma_cols[c];
    nzv[nt] = nzc[c];
  }

  // lane base pointers; A-operand layout: lane holds A[m=lane&15][k=kg*8+j]
  const ushort* a0p = Ab + (size_t)(m0 + wm * 32 + lm) * K_TOT + kg * 8;
  const ushort* a1p = a0p + 16 * K_TOT;
  const ushort* b0p = Bb + (size_t)(c0 + wn * 32 + lm) * K_TOT + kg * 8;
  const ushort* b1p = b0p + 16 * K_TOT;

  floatx4 acc[2][2];
#pragma unroll
  for (int i = 0; i < 2; ++i)
#pragma unroll
    for (int j = 0; j < 2; ++j) acc[i][j] = (floatx4){0.f, 0.f, 0.f, 0.f};

  // software-pipelined K loop (9 k-tiles of 32)
  short8 a0 = *(const short8*)(a0p);
  short8 a1 = *(const short8*)(a1p);
  short8 b0 = *(const short8*)(b0p);
  short8 b1 = *(const short8*)(b1p);
#pragma unroll
  for (int kt = 0; kt < 9; ++kt) {
    short8 na0, na1, nb0, nb1;
    if (kt < 8) {
      na0 = *(const short8*)(a0p + (kt + 1) * 32);
      na1 = *(const short8*)(a1p + (kt + 1) * 32);
      nb0 = *(const short8*)(b0p + (kt + 1) * 32);
      nb1 = *(const short8*)(b1p + (kt + 1) * 32);
    }
    acc[0][0] = __builtin_amdgcn_mfma_f32_16x16x32_bf16(a0, b0, acc[0][0], 0, 0, 0);
    acc[0][1] = __builtin_amdgcn_mfma_f32_16x16x32_bf16(a0, b1, acc[0][1], 0, 0, 0);
    acc[1][0] = __builtin_amdgcn_mfma_f32_16x16x32_bf16(a1, b0, acc[1][0], 0, 0, 0);
    acc[1][1] = __builtin_amdgcn_mfma_f32_16x16x32_bf16(a1, b1, acc[1][1], 0, 0, 0);
    if (kt == 2) {
      // pin the epilogue inputs here: forces their loads to have issued early
      // and completed by now (2 k-iterations of slack), prevents sinking
      asm volatile("" ::"v"(wbits[0]), "v"(wbits[1]), "v"(wbits[2]),
                   "v"(wbits[3]), "v"(wbits[4]), "v"(wbits[5]), "v"(wbits[6]),
                   "v"(wbits[7]));
      asm volatile("" ::"v"(grv[0]), "v"(grv[1]), "v"(grv[2]), "v"(grv[3]),
                   "v"(grv[4]), "v"(grv[5]), "v"(grv[6]), "v"(grv[7]),
                   "v"(gcv[0]), "v"(gcv[1]), "v"(nzv[0]), "v"(nzv[1]));
    }
    a0 = na0; a1 = na1; b0 = nb0; b1 = nb1;
  }

  // Epilogue: pure-register. C/D layout (m89): col=lane&15, row=(lane>>4)*4+reg
  // loss = softplus(logit) - ev*logit (branchless; ev bit = nt*16+lm of wbits)
  float lsum = 0.0f;
#pragma unroll
  for (int nt = 0; nt < 2; ++nt) {
    const int cbit = nt * 16 + lm;
#pragma unroll
    for (int mt = 0; mt < 2; ++mt) {
#pragma unroll
      for (int j = 0; j < 4; ++j) {
        const float evf = (float)((wbits[mt * 4 + j] >> cbit) & 1u);
        const float d2 = acc[mt][nt][j] + nzv[nt];
        const float dist = sqrtf(fmaxf(d2, 0.0f));
        const float logit = grv[mt * 4 + j] + gcv[nt] - dist;
        lsum += fmaxf(logit, 0.0f) + __logf(1.0f + __expf(-fabsf(logit))) -
                evf * logit;
      }
    }
  }
#pragma unroll
  for (int off = 32; off > 0; off >>= 1) lsum += __shfl_down(lsum, off);
  if (lane == 0) red[widx] = lsum;
  __syncthreads();
  if (t == 0) atomicAdd(out, red[0] + red[1] + red[2] + red[3]);
}

extern "C" void kernel_launch(void* const* d_in, const int* in_sizes, int n_in,
                              void* d_out, int out_size, void* d_ws, size_t ws_size,
                              hipStream_t stream) {
  const int* events = (const int*)d_in[0];
  const float* col_times = (const float*)d_in[1];
  const float* z_rows = (const float*)d_in[2];
  const float* z_cols = (const float*)d_in[3];
  const float* gamma_rows = (const float*)d_in[4];
  const float* gamma_cols = (const float*)d_in[5];
  float* out = (float*)d_out;

  ushort* Ab = (ushort*)d_ws;                         // 2048*288 bf16
  ushort* Bb = Ab + (size_t)R_DIM * K_TOT;            // 2048*288 bf16
  float* nzc = (float*)(Bb + (size_t)C_DIM * K_TOT);  // 2048 f32
  unsigned* Wb = (unsigned*)(nzc + C_DIM);            // 2048*64 u32 bit-pack

  prep_kernel<<<R_DIM, 256, 0, stream>>>(events, col_times, z_rows, z_cols, Ab,
                                         Bb, nzc, Wb, out);
  dim3 grid(C_DIM / 64, R_DIM / 64);
  pair_kernel<<<grid, 256, 0, stream>>>(gamma_rows, gamma_cols, Ab, Bb, nzc, Wb,
                                        out);
}

// Round 9
// 94.672 us; speedup vs baseline: 2.2094x; 1.0078x over previous
//
#include <hip/hip_runtime.h>
#include <hip/hip_bf16.h>
#include <math.h>

// Problem constants: R,C,D,ORDER = 2048,2048,64,3; O=4
#define R_DIM 2048
#define C_DIM 2048
#define D_DIM 64
// Factorization: dist^2[r,c] = sum_k A[r,k]*B[c,k] + ||zc||^2 with
//   k in [0,256): A = z_rows[o][r][d], B = -2*coef_o(t_c)*z_cols[c][d]
//   k in [256,272): A = Gram[r] (4x4 row-major), B = coef_o*coef_o' products
//   k in [272,288): zero pad
#define K_TOT 288

typedef __attribute__((ext_vector_type(8))) short short8;   // bf16x8 MFMA frag
typedef __attribute__((ext_vector_type(4))) float floatx4;  // fp32x4 acc

__device__ __forceinline__ ushort f2bf(float f) {  // RNE float->bf16
  unsigned u = __float_as_uint(f);
  return (ushort)((u + 0x7FFFu + ((u >> 16) & 1u)) >> 16);
}

// ---------------- prep: Ab/Bb bf16 matrices, nzc, event byte-pack, out=0 -----
// Event pack v2 (round-9 change): SHUFFLE-FREE. Thread t packs cols
// [t*8, t*8+8) of row b into ONE byte (bit j = col t*8+j). 32B contiguous
// load per thread (wave = dense 2KB), ~15 VALU, one byte store (block =
// dense 256B). Little-endian byte order makes Wb, viewed as u32 words,
// bit-identical to the old layout: word w of row r covers cols 32w..32w+31.
__global__ void prep_kernel(const int* __restrict__ events,
                            const float* __restrict__ col_times,
                            const float* __restrict__ z_rows,
                            const float* __restrict__ z_cols,
                            ushort* __restrict__ Ab,
                            ushort* __restrict__ Bb,
                            float* __restrict__ nzc,
                            unsigned char* __restrict__ Wb8,
                            float* __restrict__ out) {
  const int b = blockIdx.x;
  const int t = threadIdx.x;
  const int lane = t & 63;

  if (b == 0 && t == 0) out[0] = 0.0f;  // stream order: before pair_kernel

  // ---- events byte-pack: no cross-lane ops, no dependent chains ----
  {
    const int4 e0 = *(const int4*)&events[(size_t)b * C_DIM + t * 8];
    const int4 e1 = *(const int4*)&events[(size_t)b * C_DIM + t * 8 + 4];
    const unsigned byte =
        (unsigned)(e0.x & 1) | ((unsigned)(e0.y & 1) << 1) |
        ((unsigned)(e0.z & 1) << 2) | ((unsigned)(e0.w & 1) << 3) |
        ((unsigned)(e1.x & 1) << 4) | ((unsigned)(e1.y & 1) << 5) |
        ((unsigned)(e1.z & 1) << 6) | ((unsigned)(e1.w & 1) << 7);
    Wb8[(size_t)b * 256 + t] = (unsigned char)byte;
  }

  if (t < 64) {
    // ---- Ab row b ----
    float zv[4];
#pragma unroll
    for (int o = 0; o < 4; ++o) {
      zv[o] = z_rows[(size_t)(o * R_DIM + b) * D_DIM + lane];
      Ab[(size_t)b * K_TOT + o * 64 + lane] = f2bf(zv[o]);
    }
    float g00 = zv[0] * zv[0], g01 = zv[0] * zv[1], g02 = zv[0] * zv[2],
          g03 = zv[0] * zv[3], g11 = zv[1] * zv[1], g12 = zv[1] * zv[2],
          g13 = zv[1] * zv[3], g22 = zv[2] * zv[2], g23 = zv[2] * zv[3],
          g33 = zv[3] * zv[3];
#pragma unroll
    for (int off = 32; off > 0; off >>= 1) {
      g00 += __shfl_xor(g00, off); g01 += __shfl_xor(g01, off);
      g02 += __shfl_xor(g02, off); g03 += __shfl_xor(g03, off);
      g11 += __shfl_xor(g11, off); g12 += __shfl_xor(g12, off);
      g13 += __shfl_xor(g13, off); g22 += __shfl_xor(g22, off);
      g23 += __shfl_xor(g23, off); g33 += __shfl_xor(g33, off);
    }
    if (lane == 0) {
      ushort* e = Ab + (size_t)b * K_TOT + 256;  // symmetric 4x4
      e[0] = f2bf(g00);  e[1] = f2bf(g01);  e[2] = f2bf(g02);  e[3] = f2bf(g03);
      e[4] = f2bf(g01);  e[5] = f2bf(g11);  e[6] = f2bf(g12);  e[7] = f2bf(g13);
      e[8] = f2bf(g02);  e[9] = f2bf(g12);  e[10] = f2bf(g22); e[11] = f2bf(g23);
      e[12] = f2bf(g03); e[13] = f2bf(g13); e[14] = f2bf(g23); e[15] = f2bf(g33);
    }
    if (lane < 16) Ab[(size_t)b * K_TOT + 272 + lane] = 0;  // pad
  } else if (t < 128) {
    // ---- Bb row b + nzc ----
    const float tt = col_times[b];
    float cf[4];
    cf[0] = 1.0f; cf[1] = tt; cf[2] = tt * tt * 0.5f;
    cf[3] = cf[2] * tt * (1.0f / 3.0f);
    const float zc = z_cols[(size_t)b * D_DIM + lane];
#pragma unroll
    for (int o = 0; o < 4; ++o)
      Bb[(size_t)b * K_TOT + o * 64 + lane] = f2bf(-2.0f * cf[o] * zc);
    float q = zc * zc;
#pragma unroll
    for (int off = 32; off > 0; off >>= 1) q += __shfl_xor(q, off);
    if (lane == 0) {
      nzc[b] = q;
      ushort* e = Bb + (size_t)b * K_TOT + 256;
#pragma unroll
      for (int i = 0; i < 16; ++i) e[i] = f2bf(cf[i >> 2] * cf[i & 3]);
    }
    if (lane < 16) Bb[(size_t)b * K_TOT + 272 + lane] = 0;  // pad
  }
}

// ---------------- pair: register-direct MFMA GEMM (unchanged from round 8) ---
// 64x64 block tile, 4 waves in 2x2 (32x32/wave), grid 32x32 = 1024 blocks,
// 16 waves/CU. Epilogue inputs issued at kernel start, pinned mid-K-loop.
__launch_bounds__(256, 4)
__global__ void pair_kernel(const float* __restrict__ gamma_rows,
                            const float* __restrict__ gamma_cols,
                            const ushort* __restrict__ Ab,
                            const ushort* __restrict__ Bb,
                            const float* __restrict__ nzc,
                            const unsigned char* __restrict__ Wb8,
                            float* __restrict__ out) {
  __shared__ float red[4];
  const int t = threadIdx.x;
  const int widx = t >> 6, lane = t & 63;
  const int m0 = blockIdx.y * 64, c0 = blockIdx.x * 64;
  const int wm = widx & 1, wn = widx >> 1;  // wave pos in 2x2
  const int lm = lane & 15, kg = lane >> 4;

  // ---- epilogue inputs: issue FIRST, consume at the very end ----
  // u32 at byte offset r*256 + (c0>>3) + wn*4 covers cols [c0+wn*32, +32);
  // bit index for col c is c - (c0+wn*32) = nt*16+lm (LE byte order).
  const size_t wboff = (size_t)(c0 >> 3) + wn * 4;
  unsigned wbits[8];
  float grv[8];
#pragma unroll
  for (int mt = 0; mt < 2; ++mt)
#pragma unroll
    for (int j = 0; j < 4; ++j) {
      const int r = m0 + wm * 32 + mt * 16 + kg * 4 + j;
      wbits[mt * 4 + j] = *(const unsigned*)(Wb8 + (size_t)r * 256 + wboff);
      grv[mt * 4 + j] = gamma_rows[r];
    }
  float gcv[2], nzv[2];
#pragma unroll
  for (int nt = 0; nt < 2; ++nt) {
    const int c = c0 + wn * 32 + nt * 16 + lm;
    gcv[nt] = gamma_cols[c];
    nzv[nt] = nzc[c];
  }

  // lane base pointers; A-operand layout: lane holds A[m=lane&15][k=kg*8+j]
  const ushort* a0p = Ab + (size_t)(m0 + wm * 32 + lm) * K_TOT + kg * 8;
  const ushort* a1p = a0p + 16 * K_TOT;
  const ushort* b0p = Bb + (size_t)(c0 + wn * 32 + lm) * K_TOT + kg * 8;
  const ushort* b1p = b0p + 16 * K_TOT;

  floatx4 acc[2][2];
#pragma unroll
  for (int i = 0; i < 2; ++i)
#pragma unroll
    for (int j = 0; j < 2; ++j) acc[i][j] = (floatx4){0.f, 0.f, 0.f, 0.f};

  // software-pipelined K loop (9 k-tiles of 32)
  short8 a0 = *(const short8*)(a0p);
  short8 a1 = *(const short8*)(a1p);
  short8 b0 = *(const short8*)(b0p);
  short8 b1 = *(const short8*)(b1p);
#pragma unroll
  for (int kt = 0; kt < 9; ++kt) {
    short8 na0, na1, nb0, nb1;
    if (kt < 8) {
      na0 = *(const short8*)(a0p + (kt + 1) * 32);
      na1 = *(const short8*)(a1p + (kt + 1) * 32);
      nb0 = *(const short8*)(b0p + (kt + 1) * 32);
      nb1 = *(const short8*)(b1p + (kt + 1) * 32);
    }
    acc[0][0] = __builtin_amdgcn_mfma_f32_16x16x32_bf16(a0, b0, acc[0][0], 0, 0, 0);
    acc[0][1] = __builtin_amdgcn_mfma_f32_16x16x32_bf16(a0, b1, acc[0][1], 0, 0, 0);
    acc[1][0] = __builtin_amdgcn_mfma_f32_16x16x32_bf16(a1, b0, acc[1][0], 0, 0, 0);
    acc[1][1] = __builtin_amdgcn_mfma_f32_16x16x32_bf16(a1, b1, acc[1][1], 0, 0, 0);
    if (kt == 2) {
      // pin epilogue inputs: loads must have issued+completed by now,
      // cannot be sunk into the epilogue (the r4/r5 latency bug)
      asm volatile("" ::"v"(wbits[0]), "v"(wbits[1]), "v"(wbits[2]),
                   "v"(wbits[3]), "v"(wbits[4]), "v"(wbits[5]), "v"(wbits[6]),
                   "v"(wbits[7]));
      asm volatile("" ::"v"(grv[0]), "v"(grv[1]), "v"(grv[2]), "v"(grv[3]),
                   "v"(grv[4]), "v"(grv[5]), "v"(grv[6]), "v"(grv[7]),
                   "v"(gcv[0]), "v"(gcv[1]), "v"(nzv[0]), "v"(nzv[1]));
    }
    a0 = na0; a1 = na1; b0 = nb0; b1 = nb1;
  }

  // Epilogue: pure-register. C/D layout (m89): col=lane&15, row=(lane>>4)*4+reg
  // loss = softplus(logit) - ev*logit (branchless; ev bit = nt*16+lm of wbits)
  float lsum = 0.0f;
#pragma unroll
  for (int nt = 0; nt < 2; ++nt) {
    const int cbit = nt * 16 + lm;
#pragma unroll
    for (int mt = 0; mt < 2; ++mt) {
#pragma unroll
      for (int j = 0; j < 4; ++j) {
        const float evf = (float)((wbits[mt * 4 + j] >> cbit) & 1u);
        const float d2 = acc[mt][nt][j] + nzv[nt];
        const float dist = sqrtf(fmaxf(d2, 0.0f));
        const float logit = grv[mt * 4 + j] + gcv[nt] - dist;
        lsum += fmaxf(logit, 0.0f) + __logf(1.0f + __expf(-fabsf(logit))) -
                evf * logit;
      }
    }
  }
#pragma unroll
  for (int off = 32; off > 0; off >>= 1) lsum += __shfl_down(lsum, off);
  if (lane == 0) red[widx] = lsum;
  __syncthreads();
  if (t == 0) atomicAdd(out, red[0] + red[1] + red[2] + red[3]);
}

extern "C" void kernel_launch(void* const* d_in, const int* in_sizes, int n_in,
                              void* d_out, int out_size, void* d_ws, size_t ws_size,
                              hipStream_t stream) {
  const int* events = (const int*)d_in[0];
  const float* col_times = (const float*)d_in[1];
  const float* z_rows = (const float*)d_in[2];
  const float* z_cols = (const float*)d_in[3];
  const float* gamma_rows = (const float*)d_in[4];
  const float* gamma_cols = (const float*)d_in[5];
  float* out = (float*)d_out;

  ushort* Ab = (ushort*)d_ws;                         // 2048*288 bf16
  ushort* Bb = Ab + (size_t)R_DIM * K_TOT;            // 2048*288 bf16
  float* nzc = (float*)(Bb + (size_t)C_DIM * K_TOT);  // 2048 f32
  unsigned char* Wb8 = (unsigned char*)(nzc + C_DIM); // 2048*256 B byte-pack

  prep_kernel<<<R_DIM, 256, 0, stream>>>(events, col_times, z_rows, z_cols, Ab,
                                         Bb, nzc, Wb8, out);
  dim3 grid(C_DIM / 64, R_DIM / 64);
  pair_kernel<<<grid, 256, 0, stream>>>(gamma_rows, gamma_cols, Ab, Bb, nzc,
                                        Wb8, out);
}